// Round 14
// baseline (229.426 us; speedup 1.0000x reference)
//
#include <hip/hip_runtime.h>
#include <hip/hip_bf16.h>
#include <stdint.h>

#define NTOK 4096
#define DIM  256
#define NH   8
#define HD   32
#define MAXNNZ 512   // per-row neighbor list capacity (mean ~205)

typedef __attribute__((ext_vector_type(8))) short short8;
typedef __attribute__((ext_vector_type(4))) float float4v;
typedef unsigned short u16;
typedef unsigned int u32;

__device__ __forceinline__ float bf2f(u16 u) {
    union { u32 u; float f; } c; c.u = ((u32)u) << 16; return c.f;
}
__device__ __forceinline__ u16 f2bf(float f) {        // RNE
    union { float f; u32 u; } c; c.f = f;
    u32 u = c.u;
    u = u + 0x7FFFu + ((u >> 16) & 1u);
    return (u16)(u >> 16);
}

// ---------------- kernel A: x (f32) -> bf16 ----------------
__global__ void x_to_bf16(const float* __restrict__ x, u16* __restrict__ xb) {
    int i = (blockIdx.x * blockDim.x + threadIdx.x) * 4;
    float4 v = *(const float4*)(x + i);
    ushort4 o;
    o.x = f2bf(v.x); o.y = f2bf(v.y); o.z = f2bf(v.z); o.w = f2bf(v.w);
    *(ushort4*)(xb + i) = o;
}

// ---------------- kernel 0: transpose weights (f32 256x256 -> bf16 WT) ----------------
__global__ void transpose_w(const float* __restrict__ Wq, const float* __restrict__ Wk,
                            const float* __restrict__ Wv, const float* __restrict__ Wo,
                            u16* __restrict__ WT) {
    const float* srcs[4] = {Wq, Wk, Wv, Wo};
    const float* W = srcs[blockIdx.y];
    int o = blockIdx.x, i = threadIdx.x;
    WT[blockIdx.y * 65536 + o * 256 + i] = f2bf(W[i * 256 + o]);
}

// ---------------- kernel 1: adj (f32) -> per-row neighbor lists ----------------
// One block per query row; order within a list is irrelevant (softmax sum commutes).
__global__ __launch_bounds__(256) void adj_to_list(const float* __restrict__ adj,
                                                   u16* __restrict__ NL,
                                                   u32* __restrict__ NC) {
    __shared__ u32 cnt;
    int row = blockIdx.x, t = threadIdx.x;
    if (t == 0) cnt = 0;
    __syncthreads();
    const float4* rp = (const float4*)(adj + (size_t)row * NTOK);
    u16* lbase = NL + (size_t)row * MAXNNZ;
#pragma unroll
    for (int i = 0; i < 4; ++i) {
        float4 v = rp[i * 256 + t];
        u32 m = 0;
        if (v.x != 0.f) m |= 1u;
        if (v.y != 0.f) m |= 2u;
        if (v.z != 0.f) m |= 4u;
        if (v.w != 0.f) m |= 8u;
        if (m) {
            int p = __popc(m);
            u32 base = atomicAdd(&cnt, (u32)p);
            int col0 = (i * 256 + t) * 4;
            while (m) {
                int j = __builtin_ctz(m);
                m &= m - 1;
                if (base < MAXNNZ) lbase[base] = (u16)(col0 + j);
                ++base;
            }
        }
    }
    __syncthreads();
    if (t == 0) NC[row] = (cnt < MAXNNZ) ? cnt : MAXNNZ;
}

// ---------------- kernel 2: QKV projection -> Q + interleaved KV ----------------
// mat 0 -> Q (pre-scaled by 1/sqrt(HD)*log2e); mat 1 -> KV[m][0..255]; mat 2 -> KV[m][256..511]
__global__ __launch_bounds__(64) void qkv_gemm(
    const u16* __restrict__ xb,
    const u16* __restrict__ WT,
    const float* __restrict__ bq, const float* __restrict__ bk, const float* __restrict__ bv,
    u16* __restrict__ Q, u16* __restrict__ KV) {
    int lane = threadIdx.x, quad = lane >> 4, l16 = lane & 15;
    int mtile = blockIdx.x, ntile = blockIdx.y, mat = blockIdx.z;
    const float* bias = (mat == 0) ? bq : (mat == 1) ? bk : bv;
    const u16* arow = xb + (size_t)(mtile * 16 + l16) * DIM + quad * 8;
    const u16* brow = WT + (size_t)mat * 65536 + (size_t)(ntile * 16 + l16) * DIM + quad * 8;
    float4v acc = {0.f, 0.f, 0.f, 0.f};
#pragma unroll
    for (int k0 = 0; k0 < DIM; k0 += 32) {
        short8 af = *(const short8*)(arow + k0);
        short8 bf = *(const short8*)(brow + k0);
        acc = __builtin_amdgcn_mfma_f32_16x16x32_bf16(af, bf, acc, 0, 0, 0);
    }
    int n = ntile * 16 + l16;
    float bb = bias[n];
    const float sc = (mat == 0) ? 0.25503635559913516f : 1.0f;  // 1/sqrt(32)*log2e
#pragma unroll
    for (int r = 0; r < 4; ++r) {
        int m = mtile * 16 + quad * 4 + r;
        u16 o = f2bf((acc[r] + bb) * sc);
        if (mat == 0)      Q[(size_t)m * DIM + n] = o;
        else if (mat == 1) KV[(size_t)m * 512 + n] = o;
        else               KV[(size_t)m * 512 + 256 + n] = o;
    }
}

// ---------------- kernel 3: SPARSE attention, row split across 2 waves ----------------
// grid 2048 x block 256 (4 waves): wave w -> row = blk*2 + (w>>1), half = w&1.
// Lane l: dims 4l..4l+3; head = l>>3. Per neighbor: one base addr into interleaved KV
// (K at +0, V at +256 elements = offset:512B immediate), dot via 3 shfl_xor, fixed-max
// exp2, accumulate. Writes UNNORMALIZED half-plane + L partials; out_gemm merges.
__global__ __launch_bounds__(256) void sparse_attn(
    const u16* __restrict__ Q, const u16* __restrict__ KV,
    const u16* __restrict__ NL, const u32* __restrict__ NC,
    u16* __restrict__ AOp, float* __restrict__ Lp) {
    int w = threadIdx.x >> 6, lane = threadIdx.x & 63;
    int row = blockIdx.x * 2 + (w >> 1);
    int half = w & 1;
    int l4 = lane * 4;

    ushort4 qu = *(const ushort4*)(Q + (size_t)row * DIM + l4);
    float q0 = bf2f(qu.x), q1 = bf2f(qu.y), q2 = bf2f(qu.z), q3 = bf2f(qu.w);
    float O0 = 0.f, O1 = 0.f, O2 = 0.f, O3 = 0.f, lsum = 0.f;

    int nnz = (int)NC[row];
    int jbeg = half ? (nnz >> 1) : 0;
    int jend = half ? nnz : (nnz >> 1);
    const u16* lst = NL + (size_t)row * MAXNNZ;

#define NBR_BODY(kk, vv)                                                          \
    {                                                                             \
        float s = q0 * bf2f(kk.x) + q1 * bf2f(kk.y)                               \
                + q2 * bf2f(kk.z) + q3 * bf2f(kk.w);                              \
        s += __shfl_xor(s, 1, 64);                                                \
        s += __shfl_xor(s, 2, 64);                                                \
        s += __shfl_xor(s, 4, 64);                                                \
        float e = __builtin_amdgcn_exp2f(s);                                      \
        lsum += e;                                                                \
        O0 += e * bf2f(vv.x); O1 += e * bf2f(vv.y);                               \
        O2 += e * bf2f(vv.z); O3 += e * bf2f(vv.w);                               \
    }

    int j = jbeg;
    for (; j + 4 <= jend; j += 4) {
        int i0 = lst[j], i1 = lst[j + 1], i2 = lst[j + 2], i3 = lst[j + 3];
        const u16* b0 = KV + (size_t)i0 * 512 + l4;
        const u16* b1 = KV + (size_t)i1 * 512 + l4;
        const u16* b2 = KV + (size_t)i2 * 512 + l4;
        const u16* b3 = KV + (size_t)i3 * 512 + l4;
        ushort4 k0 = *(const ushort4*)(b0), v0 = *(const ushort4*)(b0 + 256);
        ushort4 k1 = *(const ushort4*)(b1), v1 = *(const ushort4*)(b1 + 256);
        ushort4 k2 = *(const ushort4*)(b2), v2 = *(const ushort4*)(b2 + 256);
        ushort4 k3 = *(const ushort4*)(b3), v3 = *(const ushort4*)(b3 + 256);
        NBR_BODY(k0, v0)
        NBR_BODY(k1, v1)
        NBR_BODY(k2, v2)
        NBR_BODY(k3, v3)
    }
    for (; j < jend; ++j) {
        const u16* b0 = KV + (size_t)lst[j] * 512 + l4;
        ushort4 k0 = *(const ushort4*)(b0), v0 = *(const ushort4*)(b0 + 256);
        NBR_BODY(k0, v0)
    }
#undef NBR_BODY

    // L partial: identical across the 8 lanes of a head group; first lane writes
    if ((lane & 7) == 0)
        Lp[(size_t)half * (NTOK * NH) + row * NH + (lane >> 3)] = lsum;
    ushort4 o;
    o.x = f2bf(O0); o.y = f2bf(O1); o.z = f2bf(O2); o.w = f2bf(O3);
    *(ushort4*)(AOp + (size_t)half * (NTOK * DIM) + (size_t)row * DIM + l4) = o;
}

// ---------------- kernel 4: output projection fused with half-merge + normalize ----------------
__global__ __launch_bounds__(64) void out_gemm(
    const u16* __restrict__ AOp, const float* __restrict__ Lp,
    const u16* __restrict__ WTo, const float* __restrict__ bo,
    float* __restrict__ out) {
    int lane = threadIdx.x, quad = lane >> 4, l16 = lane & 15;
    int mtile = blockIdx.x, ntile = blockIdx.y;
    int m = mtile * 16 + l16;
    const u16* arow0 = AOp + (size_t)m * DIM + quad * 8;
    const u16* arow1 = arow0 + (size_t)NTOK * DIM;
    const u16* brow = WTo + (size_t)(ntile * 16 + l16) * DIM + quad * 8;
    const float* lrow0 = Lp + m * NH;
    const float* lrow1 = lrow0 + NTOK * NH;
    float4v acc = {0.f, 0.f, 0.f, 0.f};
#pragma unroll
    for (int k0 = 0; k0 < DIM; k0 += 32) {
        const int h = k0 >> 5;                     // compile-time per unrolled iter
        float inv = 1.0f / (lrow0[h] + lrow1[h]);
        ushort4 a0 = *(const ushort4*)(arow0 + k0);
        ushort4 a1 = *(const ushort4*)(arow0 + k0 + 4);
        ushort4 b0 = *(const ushort4*)(arow1 + k0);
        ushort4 b1 = *(const ushort4*)(arow1 + k0 + 4);
        short8 af;
        af[0] = (short)f2bf((bf2f(a0.x) + bf2f(b0.x)) * inv);
        af[1] = (short)f2bf((bf2f(a0.y) + bf2f(b0.y)) * inv);
        af[2] = (short)f2bf((bf2f(a0.z) + bf2f(b0.z)) * inv);
        af[3] = (short)f2bf((bf2f(a0.w) + bf2f(b0.w)) * inv);
        af[4] = (short)f2bf((bf2f(a1.x) + bf2f(b1.x)) * inv);
        af[5] = (short)f2bf((bf2f(a1.y) + bf2f(b1.y)) * inv);
        af[6] = (short)f2bf((bf2f(a1.z) + bf2f(b1.z)) * inv);
        af[7] = (short)f2bf((bf2f(a1.w) + bf2f(b1.w)) * inv);
        short8 bf = *(const short8*)(brow + k0);
        acc = __builtin_amdgcn_mfma_f32_16x16x32_bf16(af, bf, acc, 0, 0, 0);
    }
    int n = ntile * 16 + l16;
    float bb = bo[n];
#pragma unroll
    for (int r = 0; r < 4; ++r)
        out[(size_t)(mtile * 16 + quad * 4 + r) * DIM + n] = acc[r] + bb;
}

extern "C" void kernel_launch(void* const* d_in, const int* in_sizes, int n_in,
                              void* d_out, int out_size, void* d_ws, size_t ws_size,
                              hipStream_t stream) {
    const float* x   = (const float*)d_in[0];
    const float* adj = (const float*)d_in[1];
    const float* Wq  = (const float*)d_in[2];
    const float* bq  = (const float*)d_in[3];
    const float* Wk  = (const float*)d_in[4];
    const float* bk  = (const float*)d_in[5];
    const float* Wv  = (const float*)d_in[6];
    const float* bv  = (const float*)d_in[7];
    const float* Wo  = (const float*)d_in[8];
    const float* bo  = (const float*)d_in[9];

    char* ws = (char*)d_ws;
    const size_t MB = 1u << 20;
    u16* Q   = (u16*)(ws);                          // 2 MB
    u16* KV  = (u16*)(ws + 2 * MB);                 // 4 MB interleaved K|V rows
    u16* WT  = (u16*)(ws + 6 * MB);                 // 512 KB
    u16* XB  = (u16*)(ws + 6 * MB + 512 * 1024);    // 2 MB
    u16* NL  = (u16*)(ws + 9 * MB);                 // 4 MB neighbor lists
    u32* NC  = (u32*)(ws + 13 * MB);                // 16 KB counts
    u16* AOp = (u16*)(ws + 14 * MB);                // 4 MB (2 half-planes bf16)
    float* Lp = (float*)(ws + 18 * MB);             // 256 KB (2 x 4096 x 8 f32)

    x_to_bf16<<<dim3(1024), 256, 0, stream>>>(x, XB);
    transpose_w<<<dim3(256, 4), 256, 0, stream>>>(Wq, Wk, Wv, Wo, WT);
    adj_to_list<<<dim3(4096), 256, 0, stream>>>(adj, NL, NC);
    qkv_gemm<<<dim3(256, 16, 3), 64, 0, stream>>>(XB, WT, bq, bk, bv, Q, KV);
    sparse_attn<<<dim3(2048), 256, 0, stream>>>(Q, KV, NL, NC, AOp, Lp);
    out_gemm<<<dim3(256, 16), 64, 0, stream>>>(AOp, Lp, WT + 3 * 65536, bo, (float*)d_out);
}

// Round 15
// 213.869 us; speedup vs baseline: 1.0727x; 1.0727x over previous
//
#include <hip/hip_runtime.h>
#include <hip/hip_bf16.h>
#include <stdint.h>

#define NTOK 4096
#define DIM  256
#define NH   8
#define HD   32
#define MAXNNZ 512   // per-row neighbor list capacity (mean ~205)

typedef __attribute__((ext_vector_type(8))) short short8;
typedef __attribute__((ext_vector_type(4))) float float4v;
typedef unsigned short u16;
typedef unsigned int u32;

__device__ __forceinline__ float bf2f(u16 u) {
    union { u32 u; float f; } c; c.u = ((u32)u) << 16; return c.f;
}
__device__ __forceinline__ u16 f2bf(float f) {        // RNE
    union { float f; u32 u; } c; c.f = f;
    u32 u = c.u;
    u = u + 0x7FFFu + ((u >> 16) & 1u);
    return (u16)(u >> 16);
}

// ---------------- kernel A: x (f32) -> bf16 ----------------
__global__ void x_to_bf16(const float* __restrict__ x, u16* __restrict__ xb) {
    int i = (blockIdx.x * blockDim.x + threadIdx.x) * 4;
    float4 v = *(const float4*)(x + i);
    ushort4 o;
    o.x = f2bf(v.x); o.y = f2bf(v.y); o.z = f2bf(v.z); o.w = f2bf(v.w);
    *(ushort4*)(xb + i) = o;
}

// ---------------- kernel 0: transpose weights (f32 256x256 -> bf16 WT) ----------------
__global__ void transpose_w(const float* __restrict__ Wq, const float* __restrict__ Wk,
                            const float* __restrict__ Wv, const float* __restrict__ Wo,
                            u16* __restrict__ WT) {
    const float* srcs[4] = {Wq, Wk, Wv, Wo};
    const float* W = srcs[blockIdx.y];
    int o = blockIdx.x, i = threadIdx.x;
    WT[blockIdx.y * 65536 + o * 256 + i] = f2bf(W[i * 256 + o]);
}

// ---------------- kernel 1: adj (f32) -> per-row neighbor lists ----------------
__global__ __launch_bounds__(256) void adj_to_list(const float* __restrict__ adj,
                                                   u16* __restrict__ NL,
                                                   u32* __restrict__ NC) {
    __shared__ u32 cnt;
    int row = blockIdx.x, t = threadIdx.x;
    if (t == 0) cnt = 0;
    __syncthreads();
    const float4* rp = (const float4*)(adj + (size_t)row * NTOK);
    u16* lbase = NL + (size_t)row * MAXNNZ;
#pragma unroll
    for (int i = 0; i < 4; ++i) {
        float4 v = rp[i * 256 + t];
        u32 m = 0;
        if (v.x != 0.f) m |= 1u;
        if (v.y != 0.f) m |= 2u;
        if (v.z != 0.f) m |= 4u;
        if (v.w != 0.f) m |= 8u;
        if (m) {
            int p = __popc(m);
            u32 base = atomicAdd(&cnt, (u32)p);
            int col0 = (i * 256 + t) * 4;
            while (m) {
                int j = __builtin_ctz(m);
                m &= m - 1;
                if (base < MAXNNZ) lbase[base] = (u16)(col0 + j);
                ++base;
            }
        }
    }
    __syncthreads();
    if (t == 0) NC[row] = (cnt < MAXNNZ) ? cnt : MAXNNZ;
}

// ---------------- kernel 2: QKV projection (bf16 inputs, row-major Q/K/V) ----------------
__global__ __launch_bounds__(64) void qkv_gemm(
    const u16* __restrict__ xb,
    const u16* __restrict__ WT,
    const float* __restrict__ bq, const float* __restrict__ bk, const float* __restrict__ bv,
    u16* __restrict__ Q, u16* __restrict__ K, u16* __restrict__ V) {
    int lane = threadIdx.x, quad = lane >> 4, l16 = lane & 15;
    int mtile = blockIdx.x, ntile = blockIdx.y, mat = blockIdx.z;
    const float* bias = (mat == 0) ? bq : (mat == 1) ? bk : bv;
    const u16* arow = xb + (size_t)(mtile * 16 + l16) * DIM + quad * 8;
    const u16* brow = WT + (size_t)mat * 65536 + (size_t)(ntile * 16 + l16) * DIM + quad * 8;
    float4v acc = {0.f, 0.f, 0.f, 0.f};
#pragma unroll
    for (int k0 = 0; k0 < DIM; k0 += 32) {
        short8 af = *(const short8*)(arow + k0);
        short8 bf = *(const short8*)(brow + k0);
        acc = __builtin_amdgcn_mfma_f32_16x16x32_bf16(af, bf, acc, 0, 0, 0);
    }
    int n = ntile * 16 + l16;
    float bb = bias[n];
    const float sc = (mat == 0) ? 0.25503635559913516f : 1.0f;  // 1/sqrt(32)*log2e
    u16* dst = (mat == 0) ? Q : (mat == 1) ? K : V;
#pragma unroll
    for (int r = 0; r < 4; ++r) {
        int m = mtile * 16 + quad * 4 + r;
        dst[(size_t)m * DIM + n] = f2bf((acc[r] + bb) * sc);
    }
}

// ---------------- kernel 3: SPARSE attention, 8-neighbor gather batches ----------------
// One wave per query row (all 8 heads). Lane l: dims 4l..4l+3; head = l>>3.
// Batch 8 neighbors: 16 gathers issued back-to-back (partial vmcnt waits let
// compute on nbr 0 overlap arrivals of 1..7) -> first-load latency paid once/8.
__global__ __launch_bounds__(256, 4) void sparse_attn(
    const u16* __restrict__ Q, const u16* __restrict__ K, const u16* __restrict__ V,
    const u16* __restrict__ NL, const u32* __restrict__ NC,
    u16* __restrict__ AO) {
    int row = blockIdx.x * 4 + (threadIdx.x >> 6);
    int lane = threadIdx.x & 63;
    int l4 = lane * 4;

    ushort4 qu = *(const ushort4*)(Q + (size_t)row * DIM + l4);
    float q0 = bf2f(qu.x), q1 = bf2f(qu.y), q2 = bf2f(qu.z), q3 = bf2f(qu.w);
    float O0 = 0.f, O1 = 0.f, O2 = 0.f, O3 = 0.f, lsum = 0.f;

    int nnz = (int)NC[row];
    const u16* lst = NL + (size_t)row * MAXNNZ;

#define NBR_BODY(kk, vv)                                                          \
    {                                                                             \
        float s = q0 * bf2f(kk.x) + q1 * bf2f(kk.y)                               \
                + q2 * bf2f(kk.z) + q3 * bf2f(kk.w);                              \
        s += __shfl_xor(s, 1, 64);                                                \
        s += __shfl_xor(s, 2, 64);                                                \
        s += __shfl_xor(s, 4, 64);                                                \
        float e = __builtin_amdgcn_exp2f(s);                                      \
        lsum += e;                                                                \
        O0 += e * bf2f(vv.x); O1 += e * bf2f(vv.y);                               \
        O2 += e * bf2f(vv.z); O3 += e * bf2f(vv.w);                               \
    }

    int j = 0;
    for (; j + 8 <= nnz; j += 8) {
        ushort4 i03 = *(const ushort4*)(lst + j);
        ushort4 i47 = *(const ushort4*)(lst + j + 4);
        ushort4 kk[8], vv[8];
        kk[0] = *(const ushort4*)(K + (size_t)i03.x * DIM + l4);
        kk[1] = *(const ushort4*)(K + (size_t)i03.y * DIM + l4);
        kk[2] = *(const ushort4*)(K + (size_t)i03.z * DIM + l4);
        kk[3] = *(const ushort4*)(K + (size_t)i03.w * DIM + l4);
        kk[4] = *(const ushort4*)(K + (size_t)i47.x * DIM + l4);
        kk[5] = *(const ushort4*)(K + (size_t)i47.y * DIM + l4);
        kk[6] = *(const ushort4*)(K + (size_t)i47.z * DIM + l4);
        kk[7] = *(const ushort4*)(K + (size_t)i47.w * DIM + l4);
        vv[0] = *(const ushort4*)(V + (size_t)i03.x * DIM + l4);
        vv[1] = *(const ushort4*)(V + (size_t)i03.y * DIM + l4);
        vv[2] = *(const ushort4*)(V + (size_t)i03.z * DIM + l4);
        vv[3] = *(const ushort4*)(V + (size_t)i03.w * DIM + l4);
        vv[4] = *(const ushort4*)(V + (size_t)i47.x * DIM + l4);
        vv[5] = *(const ushort4*)(V + (size_t)i47.y * DIM + l4);
        vv[6] = *(const ushort4*)(V + (size_t)i47.z * DIM + l4);
        vv[7] = *(const ushort4*)(V + (size_t)i47.w * DIM + l4);
#pragma unroll
        for (int t = 0; t < 8; ++t) NBR_BODY(kk[t], vv[t])
    }
    for (; j + 4 <= nnz; j += 4) {
        ushort4 i03 = *(const ushort4*)(lst + j);
        ushort4 k0 = *(const ushort4*)(K + (size_t)i03.x * DIM + l4);
        ushort4 k1 = *(const ushort4*)(K + (size_t)i03.y * DIM + l4);
        ushort4 k2 = *(const ushort4*)(K + (size_t)i03.z * DIM + l4);
        ushort4 k3 = *(const ushort4*)(K + (size_t)i03.w * DIM + l4);
        ushort4 v0 = *(const ushort4*)(V + (size_t)i03.x * DIM + l4);
        ushort4 v1 = *(const ushort4*)(V + (size_t)i03.y * DIM + l4);
        ushort4 v2 = *(const ushort4*)(V + (size_t)i03.z * DIM + l4);
        ushort4 v3 = *(const ushort4*)(V + (size_t)i03.w * DIM + l4);
        NBR_BODY(k0, v0)
        NBR_BODY(k1, v1)
        NBR_BODY(k2, v2)
        NBR_BODY(k3, v3)
    }
    for (; j < nnz; ++j) {
        int i0 = lst[j];
        ushort4 k0 = *(const ushort4*)(K + (size_t)i0 * DIM + l4);
        ushort4 v0 = *(const ushort4*)(V + (size_t)i0 * DIM + l4);
        NBR_BODY(k0, v0)
    }
#undef NBR_BODY

    float inv = 1.0f / lsum;
    ushort4 o;
    o.x = f2bf(O0 * inv); o.y = f2bf(O1 * inv);
    o.z = f2bf(O2 * inv); o.w = f2bf(O3 * inv);
    *(ushort4*)(AO + (size_t)row * DIM + l4) = o;
}

// ---------------- kernel 4: output projection (f32 out) ----------------
__global__ __launch_bounds__(64) void out_gemm(
    const u16* __restrict__ AO, const u16* __restrict__ WTo, const float* __restrict__ bo,
    float* __restrict__ out) {
    int lane = threadIdx.x, quad = lane >> 4, l16 = lane & 15;
    int mtile = blockIdx.x, ntile = blockIdx.y;
    const u16* arow = AO + (size_t)(mtile * 16 + l16) * DIM + quad * 8;
    const u16* brow = WTo + (size_t)(ntile * 16 + l16) * DIM + quad * 8;
    float4v acc = {0.f, 0.f, 0.f, 0.f};
#pragma unroll
    for (int k0 = 0; k0 < DIM; k0 += 32) {
        short8 af = *(const short8*)(arow + k0);
        short8 bf = *(const short8*)(brow + k0);
        acc = __builtin_amdgcn_mfma_f32_16x16x32_bf16(af, bf, acc, 0, 0, 0);
    }
    int n = ntile * 16 + l16;
    float bb = bo[n];
#pragma unroll
    for (int r = 0; r < 4; ++r)
        out[(size_t)(mtile * 16 + quad * 4 + r) * DIM + n] = acc[r] + bb;
}

extern "C" void kernel_launch(void* const* d_in, const int* in_sizes, int n_in,
                              void* d_out, int out_size, void* d_ws, size_t ws_size,
                              hipStream_t stream) {
    const float* x   = (const float*)d_in[0];
    const float* adj = (const float*)d_in[1];
    const float* Wq  = (const float*)d_in[2];
    const float* bq  = (const float*)d_in[3];
    const float* Wk  = (const float*)d_in[4];
    const float* bk  = (const float*)d_in[5];
    const float* Wv  = (const float*)d_in[6];
    const float* bv  = (const float*)d_in[7];
    const float* Wo  = (const float*)d_in[8];
    const float* bo  = (const float*)d_in[9];

    char* ws = (char*)d_ws;
    const size_t MB = 1u << 20;
    u16* Q   = (u16*)(ws);                          // 2 MB
    u16* K   = (u16*)(ws + 2 * MB);                 // 2 MB
    u16* V   = (u16*)(ws + 4 * MB);                 // 2 MB
    u16* AO  = (u16*)(ws + 6 * MB);                 // 2 MB
    u16* WT  = (u16*)(ws + 8 * MB);                 // 512 KB
    u16* XB  = (u16*)(ws + 8 * MB + 512 * 1024);    // 2 MB
    u16* NL  = (u16*)(ws + 11 * MB);                // 4 MB neighbor lists
    u32* NC  = (u32*)(ws + 15 * MB);                // 16 KB counts

    x_to_bf16<<<dim3(1024), 256, 0, stream>>>(x, XB);
    transpose_w<<<dim3(256, 4), 256, 0, stream>>>(Wq, Wk, Wv, Wo, WT);
    adj_to_list<<<dim3(4096), 256, 0, stream>>>(adj, NL, NC);
    qkv_gemm<<<dim3(256, 16, 3), 64, 0, stream>>>(XB, WT, bq, bk, bv, Q, K, V);
    sparse_attn<<<dim3(1024), 256, 0, stream>>>(Q, K, V, NL, NC, AO);
    out_gemm<<<dim3(256, 16), 64, 0, stream>>>(AO, WT + 3 * 65536, bo, (float*)d_out);
}